// Round 4
// baseline (66131.921 us; speedup 1.0000x reference)
//
#include <hip/hip_runtime.h>
#include <hip/hip_fp16.h>

#define T_STEPS 2048
#define BATCH   32
#define DIM     1024
#define NSLICE  8
#define SLICE_COLS 128   // DIM / NSLICE

typedef _Float16 half2_t __attribute__((ext_vector_type(2)));
typedef _Float16 f16x8  __attribute__((ext_vector_type(8)));
typedef float    f32x4  __attribute__((ext_vector_type(4)));

__device__ __forceinline__ float fdot2(unsigned a, unsigned b, float c) {
#if defined(__has_builtin) && __has_builtin(__builtin_amdgcn_fdot2)
    return __builtin_amdgcn_fdot2(__builtin_bit_cast(half2_t, a),
                                  __builtin_bit_cast(half2_t, b), c, false);
#else
    float d;
    asm("v_dot2_f32_f16 %0, %1, %2, %3" : "=v"(d) : "v"(a), "v"(b), "v"(c));
    return d;
#endif
}

// ---------------------------------------------------------------------------
// Kernel 0: zero cross-wg flags (d_ws is not re-poisoned between replays).
// ---------------------------------------------------------------------------
__global__ void flag_init(int* __restrict__ flags) {
    flags[threadIdx.x] = 0;
}

// ---------------------------------------------------------------------------
// Kernel 1: repack W_h (fp32 [k][n]) -> f16 pairs P[n][m], m=k>>1 packing
// (W[2m][n], W[2m+1][n]) into one dword.
// ---------------------------------------------------------------------------
__global__ void conv_pack(const float* __restrict__ Wh, unsigned* __restrict__ P) {
    const int i = blockIdx.x * blockDim.x + threadIdx.x;   // 0 .. DIM*DIM/2-1
    const int n = i & (DIM - 1);
    const int m = i >> 10;                                  // pair index 0..511
    half2_t p;
    p[0] = (_Float16)Wh[(size_t)(2 * m)     * DIM + n];
    p[1] = (_Float16)Wh[(size_t)(2 * m + 1) * DIM + n];
    P[(size_t)n * (DIM / 2) + m] = __builtin_bit_cast(unsigned, p);
}

// ---------------------------------------------------------------------------
// Kernel 2: xW = x @ W_x + b  (MFMA 16x16x32, 128x128 tile) -> h_all[1:]
// ---------------------------------------------------------------------------
#define BM 128
#define BN 128
#define BK 32
#define LDT 40

__global__ __launch_bounds__(256) void gemm_xw(
    const float* __restrict__ X,
    const float* __restrict__ Wx,
    const float* __restrict__ bias,
    float* __restrict__ out)
{
    __shared__ _Float16 As[BM][LDT];
    __shared__ _Float16 Bs[BN][LDT];

    const int tid  = threadIdx.x;
    const int m0   = blockIdx.x * BM;
    const int n0   = blockIdx.y * BN;
    const int lane = tid & 63;
    const int wid  = tid >> 6;
    const int wm   = (wid >> 1) * 64;
    const int wn   = (wid & 1) * 64;
    const int lr   = lane & 15;
    const int lk   = (lane >> 4) * 8;

    const int ar = tid >> 1,  ac = (tid & 1) * 16;
    const int bk = tid >> 3,  bn = (tid & 7) * 16;

    f32x4 acc[4][4] = {};

    for (int k0 = 0; k0 < DIM; k0 += BK) {
        __syncthreads();
        {
            const float* src = X + (size_t)(m0 + ar) * DIM + k0 + ac;
            float4 q0 = *(const float4*)(src + 0);
            float4 q1 = *(const float4*)(src + 4);
            float4 q2 = *(const float4*)(src + 8);
            float4 q3 = *(const float4*)(src + 12);
            f16x8 p0, p1;
            p0[0] = (_Float16)q0.x; p0[1] = (_Float16)q0.y;
            p0[2] = (_Float16)q0.z; p0[3] = (_Float16)q0.w;
            p0[4] = (_Float16)q1.x; p0[5] = (_Float16)q1.y;
            p0[6] = (_Float16)q1.z; p0[7] = (_Float16)q1.w;
            p1[0] = (_Float16)q2.x; p1[1] = (_Float16)q2.y;
            p1[2] = (_Float16)q2.z; p1[3] = (_Float16)q2.w;
            p1[4] = (_Float16)q3.x; p1[5] = (_Float16)q3.y;
            p1[6] = (_Float16)q3.z; p1[7] = (_Float16)q3.w;
            *(f16x8*)&As[ar][ac]     = p0;
            *(f16x8*)&As[ar][ac + 8] = p1;
        }
        {
            const float* src = Wx + (size_t)(k0 + bk) * DIM + n0 + bn;
            float4 q0 = *(const float4*)(src + 0);
            float4 q1 = *(const float4*)(src + 4);
            float4 q2 = *(const float4*)(src + 8);
            float4 q3 = *(const float4*)(src + 12);
            float vv[16];
            *(float4*)&vv[0]  = q0; *(float4*)&vv[4]  = q1;
            *(float4*)&vv[8]  = q2; *(float4*)&vv[12] = q3;
            #pragma unroll
            for (int i = 0; i < 16; ++i) Bs[bn + i][bk] = (_Float16)vv[i];
        }
        __syncthreads();
        f16x8 a[4], bb[4];
        #pragma unroll
        for (int f = 0; f < 4; ++f) a[f]  = *(const f16x8*)&As[wm + f * 16 + lr][lk];
        #pragma unroll
        for (int f = 0; f < 4; ++f) bb[f] = *(const f16x8*)&Bs[wn + f * 16 + lr][lk];
        #pragma unroll
        for (int i = 0; i < 4; ++i)
            #pragma unroll
            for (int j = 0; j < 4; ++j)
                acc[i][j] = __builtin_amdgcn_mfma_f32_16x16x32_f16(
                    a[i], bb[j], acc[i][j], 0, 0, 0);
    }

    #pragma unroll
    for (int i = 0; i < 4; ++i) {
        #pragma unroll
        for (int j = 0; j < 4; ++j) {
            const int col = n0 + wn + j * 16 + lr;
            const float bv = bias[col];
            #pragma unroll
            for (int r = 0; r < 4; ++r) {
                const int row = m0 + wm + i * 16 + (lane >> 4) * 4 + r;
                __builtin_nontemporal_store(acc[i][j][r] + bv,
                                            out + (size_t)row * DIM + col);
            }
        }
    }
}

// ---------------------------------------------------------------------------
// Kernel 3: recurrence. 256 wgs = (32 rows x 8 column-slices), 1 per CU
// (__launch_bounds__(1024,4): 128-VGPR budget). W slice (64 VGPRs/thread) is
// PINNED into registers with empty asm — rounds 2/3 proved the allocator
// otherwise remats the loads into the t-loop (VGPR_Count=48 < 64), which,
// combined with the per-step agent-acquire L2 invalidate, re-streamed W from
// L3 every step (~32us/step).
// ---------------------------------------------------------------------------
__global__ __launch_bounds__(1024, 4) void elman_rec(
    const float* __restrict__ h0,
    const unsigned* __restrict__ P,   // packed W_h
    float* __restrict__ hs,           // [T][B][D]
    float* __restrict__ h_all,        // [T+1][B][D]; [1:] pre-filled with xW
    int* __restrict__ flags)          // [BATCH][NSLICE]
{
    const int blk = blockIdx.x;
    const int b   = blk & 31;         // row; b%8 == XCD for all 8 slices
    const int s   = blk >> 5;         // column-slice

    const int tid   = threadIdx.x;
    const int col_l = tid >> 3;               // 0..127
    const int ks    = tid & 7;                // k-chunk
    const int col   = s * SLICE_COLS + col_l;

    // skewed f16 h buffer: chunk c at byte c*272 (256B payload + 16B skew)
    __shared__ alignas(16) _Float16 hbuf[8 * 136];

    // ---- W slice -> registers (64 VGPRs/thread; 256 KB/CU), then PIN.
    uint4 wv[16];
    {
        const uint4* wp = (const uint4*)P + (size_t)col * (DIM / 8) + ks * 16;
        #pragma unroll
        for (int r = 0; r < 16; ++r) wv[r] = wp[r];
    }
    #pragma unroll
    for (int r = 0; r < 16; ++r) {
        asm volatile("" : "+v"(wv[r].x), "+v"(wv[r].y),
                          "+v"(wv[r].z), "+v"(wv[r].w));
    }

    // ---- init h0
    {
        const float h0v = h0[(size_t)b * DIM + tid];
        h_all[(size_t)b * DIM + tid] = h0v;
        hbuf[(tid >> 7) * 136 + (tid & 127)] = (_Float16)h0v;
    }
    __syncthreads();

    for (int t = 0; t < T_STEPS; ++t) {
        float* slot = h_all + ((size_t)(t + 1) * BATCH + b) * DIM;

        // xW for my column (own slice only; overwritten below by own wg)
        const float xw = slot[col];

        // ---- dot over my k-chunk: W in registers, h broadcast from LDS
        float z = 0.0f;
        const char* hb = (const char*)hbuf + ks * 272;
        #pragma unroll
        for (int r = 0; r < 16; ++r) {
            const uint4 hh = *(const uint4*)(hb + r * 16);
            z = fdot2(hh.x, wv[r].x, z);
            z = fdot2(hh.y, wv[r].y, z);
            z = fdot2(hh.z, wv[r].z, z);
            z = fdot2(hh.w, wv[r].w, z);
        }
        z += __shfl_xor(z, 1);
        z += __shfl_xor(z, 2);
        z += __shfl_xor(z, 4);

        if (ks == 0) {
            const float zz = z + xw;
            const float e  = __expf(2.0f * zz);
            const float hn = 1.0f - 2.0f / (e + 1.0f);
            __hip_atomic_store(slot + col, hn, __ATOMIC_RELAXED,
                               __HIP_MEMORY_SCOPE_AGENT);
        }
        __syncthreads();   // all waves' stores drained (vmcnt(0) before barrier)
        if (tid == 0)
            __hip_atomic_store(flags + b * NSLICE + s, t + 1, __ATOMIC_RELEASE,
                               __HIP_MEMORY_SCOPE_AGENT);

        // ---- 8 threads wait on the 7 peer slices
        if (tid < NSLICE && tid != s) {
            const int* fp = flags + b * NSLICE + tid;
            int guard = 0;
            while (__hip_atomic_load(fp, __ATOMIC_RELAXED,
                                     __HIP_MEMORY_SCOPE_AGENT) < t + 1) {
                if (++guard > (1 << 22)) break;   // fail loud, not hung
            }
        }
        __syncthreads();
        __builtin_amdgcn_fence(__ATOMIC_ACQUIRE, "agent");

        // ---- restage full h row from L3; emit hs[t] coalesced
        const float v = slot[tid];
        hbuf[(tid >> 7) * 136 + (tid & 127)] = (_Float16)v;
        __builtin_nontemporal_store(v, hs + ((size_t)t * BATCH + b) * DIM + tid);
        __syncthreads();
    }
}

extern "C" void kernel_launch(void* const* d_in, const int* in_sizes, int n_in,
                              void* d_out, int out_size, void* d_ws, size_t ws_size,
                              hipStream_t stream) {
    const float* x    = (const float*)d_in[0];   // [T][B][D]
    const float* h0   = (const float*)d_in[1];   // [B][D]
    const float* Wx   = (const float*)d_in[2];   // [D][D]
    const float* Wh   = (const float*)d_in[3];   // [D][D]
    const float* bias = (const float*)d_in[4];   // [D]

    float* hs    = (float*)d_out;
    float* h_all = hs + (size_t)T_STEPS * BATCH * DIM;

    int*      flags = (int*)d_ws;                               // 1 KB
    unsigned* P     = (unsigned*)((char*)d_ws + 4096);          // 2 MB packed W_h

    flag_init<<<1, BATCH * NSLICE, 0, stream>>>(flags);

    conv_pack<<<(DIM * DIM / 2) / 256, 256, 0, stream>>>(Wh, P);

    dim3 g((T_STEPS * BATCH) / BM, DIM / BN);
    gemm_xw<<<g, 256, 0, stream>>>(x, Wx, bias, h_all + (size_t)BATCH * DIM);

    elman_rec<<<BATCH * NSLICE, 1024, 0, stream>>>(h0, P, hs, h_all, flags);
}

// Round 5
// 10191.459 us; speedup vs baseline: 6.4890x; 6.4890x over previous
//
#include <hip/hip_runtime.h>
#include <hip/hip_fp16.h>

#define T_STEPS 2048
#define BATCH   32
#define DIM     1024
#define NWG     32      // rec workgroups; wg owns 32 output cols
#define WCOLS   32

typedef _Float16 f16x8 __attribute__((ext_vector_type(8)));
typedef float    f32x4 __attribute__((ext_vector_type(4)));

__device__ __forceinline__ f16x8 cvt8(f32x4 a, f32x4 b) {
    f16x8 r;
    r[0]=(_Float16)a[0]; r[1]=(_Float16)a[1]; r[2]=(_Float16)a[2]; r[3]=(_Float16)a[3];
    r[4]=(_Float16)b[0]; r[5]=(_Float16)b[1]; r[6]=(_Float16)b[2]; r[7]=(_Float16)b[3];
    return r;
}

// coherent 16B ops: bypass L1/L2, hit the L3 coherence point. No fences anywhere.
__device__ __forceinline__ void store_coh16(float* p, f32x4 v) {
    asm volatile("global_store_dwordx4 %0, %1, off sc0 sc1" :: "v"(p), "v"(v) : "memory");
}
__device__ __forceinline__ void load_coh16(const float* p, f32x4& v) {
    asm volatile("global_load_dwordx4 %0, %1, off sc0 sc1" : "=v"(v) : "v"(p) : "memory");
}

// ---------------------------------------------------------------------------
// flags zeroed every launch (graph replays don't re-poison d_ws)
// ---------------------------------------------------------------------------
__global__ void flag_init(int* __restrict__ flags) { flags[threadIdx.x] = 0; }

// ---------------------------------------------------------------------------
// repack W_h (fp32 [k][n]) -> f16, B-fragment-swizzled blocks:
// P[n][pos][e] where blk=k>>3, e=k&7, pos = blk ^ (n&7)  (16B-block XOR swizzle)
// ---------------------------------------------------------------------------
__global__ void conv_pack(const float* __restrict__ Wh, _Float16* __restrict__ P) {
    const int idx = blockIdx.x * blockDim.x + threadIdx.x;  // DIM*DIM
    const int k = idx >> 10, n = idx & (DIM - 1);
    const int pos = (k >> 3) ^ (n & 7);
    P[(size_t)n * 1024 + pos * 8 + (k & 7)] = (_Float16)Wh[idx];
}

// ---------------------------------------------------------------------------
// xW = x @ W_x + b  (validated in rounds 1-4, unchanged) -> h_all[1:]
// ---------------------------------------------------------------------------
#define BM 128
#define BN 128
#define BK 32
#define LDT 40

__global__ __launch_bounds__(256) void gemm_xw(
    const float* __restrict__ X, const float* __restrict__ Wx,
    const float* __restrict__ bias, float* __restrict__ out)
{
    __shared__ _Float16 As[BM][LDT];
    __shared__ _Float16 Bs[BN][LDT];

    const int tid = threadIdx.x;
    const int m0 = blockIdx.x * BM, n0 = blockIdx.y * BN;
    const int lane = tid & 63, wid = tid >> 6;
    const int wm = (wid >> 1) * 64, wn = (wid & 1) * 64;
    const int lr = lane & 15, lk = (lane >> 4) * 8;
    const int ar = tid >> 1, ac = (tid & 1) * 16;
    const int bk = tid >> 3, bn = (tid & 7) * 16;

    f32x4 acc[4][4] = {};

    for (int k0 = 0; k0 < DIM; k0 += BK) {
        __syncthreads();
        {
            const float* src = X + (size_t)(m0 + ar) * DIM + k0 + ac;
            float4 q0 = *(const float4*)(src + 0);
            float4 q1 = *(const float4*)(src + 4);
            float4 q2 = *(const float4*)(src + 8);
            float4 q3 = *(const float4*)(src + 12);
            f16x8 p0, p1;
            p0[0]=(_Float16)q0.x; p0[1]=(_Float16)q0.y; p0[2]=(_Float16)q0.z; p0[3]=(_Float16)q0.w;
            p0[4]=(_Float16)q1.x; p0[5]=(_Float16)q1.y; p0[6]=(_Float16)q1.z; p0[7]=(_Float16)q1.w;
            p1[0]=(_Float16)q2.x; p1[1]=(_Float16)q2.y; p1[2]=(_Float16)q2.z; p1[3]=(_Float16)q2.w;
            p1[4]=(_Float16)q3.x; p1[5]=(_Float16)q3.y; p1[6]=(_Float16)q3.z; p1[7]=(_Float16)q3.w;
            *(f16x8*)&As[ar][ac] = p0;
            *(f16x8*)&As[ar][ac + 8] = p1;
        }
        {
            const float* src = Wx + (size_t)(k0 + bk) * DIM + n0 + bn;
            float4 q0 = *(const float4*)(src + 0);
            float4 q1 = *(const float4*)(src + 4);
            float4 q2 = *(const float4*)(src + 8);
            float4 q3 = *(const float4*)(src + 12);
            float vv[16];
            *(float4*)&vv[0] = q0; *(float4*)&vv[4] = q1;
            *(float4*)&vv[8] = q2; *(float4*)&vv[12] = q3;
            #pragma unroll
            for (int i = 0; i < 16; ++i) Bs[bn + i][bk] = (_Float16)vv[i];
        }
        __syncthreads();
        f16x8 a[4], bb[4];
        #pragma unroll
        for (int f = 0; f < 4; ++f) a[f]  = *(const f16x8*)&As[wm + f * 16 + lr][lk];
        #pragma unroll
        for (int f = 0; f < 4; ++f) bb[f] = *(const f16x8*)&Bs[wn + f * 16 + lr][lk];
        #pragma unroll
        for (int i = 0; i < 4; ++i)
            #pragma unroll
            for (int j = 0; j < 4; ++j)
                acc[i][j] = __builtin_amdgcn_mfma_f32_16x16x32_f16(a[i], bb[j], acc[i][j], 0, 0, 0);
    }

    #pragma unroll
    for (int i = 0; i < 4; ++i)
        #pragma unroll
        for (int j = 0; j < 4; ++j) {
            const int col = n0 + wn + j * 16 + lr;
            const float bv = bias[col];
            #pragma unroll
            for (int r = 0; r < 4; ++r) {
                const int row = m0 + wm + i * 16 + (lane >> 4) * 4 + r;
                __builtin_nontemporal_store(acc[i][j][r] + bv, out + (size_t)row * DIM + col);
            }
        }
}

// ---------------------------------------------------------------------------
// recurrence: 32 wgs x 256 thr (4 waves). W-slice and h both LDS-resident.
// Per step: h(32x1024,f16,LDS) @ Wslice(1024x32,f16,LDS) via MFMA (K-split
// over 4 waves) -> +xW -> tanh -> h_all[t+1] (sc0sc1 = exchange + output),
// flags (relaxed agent), poll, reload h_all[t+1] via sc0sc1 -> Hs.
// Addresses monotonic in t => no buffer-reuse race. No fences, no L2 flush.
// ---------------------------------------------------------------------------
__global__ __launch_bounds__(256, 1) void elman_rec(
    const float* __restrict__ h0, const _Float16* __restrict__ P,
    float* __restrict__ hs, float* __restrict__ h_all, int* __restrict__ flags)
{
    __shared__ _Float16 Hs[32 * 128 * 8];   // [row][pos][8]  64 KB
    __shared__ _Float16 Ws[32 * 128 * 8];   // [colL][pos][8] 64 KB
    __shared__ float    Ht2[4][32][36];     // K-split partials, 18 KB

    const int wg  = blockIdx.x;
    const int tid = threadIdx.x;
    const int w = tid >> 6, lane = tid & 63, lr = lane & 15, kg = lane >> 4;
    const int wcol0 = wg * WCOLS;

    // ---- stage W slice (linear 64KB copy; swizzle pre-baked by conv_pack)
    {
        const uint4* src = (const uint4*)(P + (size_t)wcol0 * 1024);
        uint4* dst = (uint4*)Ws;
        #pragma unroll
        for (int j = 0; j < 16; ++j) dst[tid + 256 * j] = src[tid + 256 * j];
    }
    // ---- stage h0 -> Hs (f16, swizzled); wg0 also writes h_all[0] = h0
    #pragma unroll
    for (int j = 0; j < 16; ++j) {
        const int bi = tid + 256 * j;              // 4096 blocks of 8 elems
        const int r = bi >> 7, blk = bi & 127;
        f32x4 q0 = *(const f32x4*)(h0 + (size_t)r * DIM + blk * 8);
        f32x4 q1 = *(const f32x4*)(h0 + (size_t)r * DIM + blk * 8 + 4);
        *(f16x8*)&Hs[((r << 7) + (blk ^ (r & 7))) * 8] = cvt8(q0, q1);
        if (wg == 0) {
            *(f32x4*)(h_all + (size_t)r * DIM + blk * 8)     = q0;
            *(f32x4*)(h_all + (size_t)r * DIM + blk * 8 + 4) = q1;
        }
    }
    __syncthreads();

    const int er = tid >> 3, ec4 = (tid & 7) * 4;   // emit-pass coords

    for (int t = 0; t < T_STEPS; ++t) {
        float* slot = h_all + (size_t)(t + 1) * (BATCH * DIM);

        // xW for emit (issued early, hidden under MFMA)
        f32x4 xw = *(const f32x4*)(slot + (size_t)er * DIM + wcol0 + ec4);

        // ---- MFMA, K-split: wave w covers k in [w*256, w*256+256)
        f32x4 a00 = {0,0,0,0}, a01 = {0,0,0,0}, a10 = {0,0,0,0}, a11 = {0,0,0,0};
        #pragma unroll
        for (int q = 0; q < 8; ++q) {
            const int blk = (w * 8 + q) * 4 + kg;
            const int pa = blk ^ (lr & 7);
            f16x8 A0 = *(const f16x8*)&Hs[((lr << 7)        + pa) * 8];
            f16x8 A1 = *(const f16x8*)&Hs[(((16 + lr) << 7) + pa) * 8];
            f16x8 B0 = *(const f16x8*)&Ws[((lr << 7)        + pa) * 8];
            f16x8 B1 = *(const f16x8*)&Ws[(((16 + lr) << 7) + pa) * 8];
            a00 = __builtin_amdgcn_mfma_f32_16x16x32_f16(A0, B0, a00, 0, 0, 0);
            a01 = __builtin_amdgcn_mfma_f32_16x16x32_f16(A0, B1, a01, 0, 0, 0);
            a10 = __builtin_amdgcn_mfma_f32_16x16x32_f16(A1, B0, a10, 0, 0, 0);
            a11 = __builtin_amdgcn_mfma_f32_16x16x32_f16(A1, B1, a11, 0, 0, 0);
        }
        #pragma unroll
        for (int r = 0; r < 4; ++r) {
            Ht2[w][kg * 4 + r]      [lr]      = a00[r];
            Ht2[w][kg * 4 + r]      [16 + lr] = a01[r];
            Ht2[w][16 + kg * 4 + r] [lr]      = a10[r];
            Ht2[w][16 + kg * 4 + r] [16 + lr] = a11[r];
        }
        __syncthreads();

        // ---- emit: reduce K-partials, +xW, tanh, store (output == exchange)
        f32x4 z = xw;
        #pragma unroll
        for (int ww = 0; ww < 4; ++ww) z += *(const f32x4*)&Ht2[ww][er][ec4];
        f32x4 h;
        #pragma unroll
        for (int i = 0; i < 4; ++i) {
            const float e = __expf(2.0f * z[i]);
            h[i] = 1.0f - 2.0f / (e + 1.0f);
        }
        __builtin_nontemporal_store(h, (f32x4*)(hs + (size_t)t * (BATCH * DIM)
                                                + (size_t)er * DIM + wcol0 + ec4));
        store_coh16(slot + (size_t)er * DIM + wcol0 + ec4, h);

        if (t == T_STEPS - 1) break;

        __syncthreads();   // drains vmcnt -> data globally visible before flag
        if (tid == 0)
            __hip_atomic_store(flags + wg * 16, t + 1, __ATOMIC_RELAXED,
                               __HIP_MEMORY_SCOPE_AGENT);
        if (tid < NWG) {
            int g = 0;
            while (__hip_atomic_load(flags + tid * 16, __ATOMIC_RELAXED,
                                     __HIP_MEMORY_SCOPE_AGENT) < t + 1) {
                if (++g > (1 << 20)) break;    // fail loud, not hung
            }
        }
        __syncthreads();

        // ---- reload full h_{t+1} (32x1024 f32) via coherent loads -> Hs
        #pragma unroll
        for (int half = 0; half < 4; ++half) {
            f32x4 q[8];
            #pragma unroll
            for (int u = 0; u < 4; ++u) {
                const int bi = tid + 256 * (half * 4 + u);
                const float* ap = slot + (size_t)(bi >> 7) * DIM + (bi & 127) * 8;
                load_coh16(ap,     q[2 * u]);
                load_coh16(ap + 4, q[2 * u + 1]);
            }
            asm volatile("s_waitcnt vmcnt(0)" ::: "memory");
            __builtin_amdgcn_sched_barrier(0);
            #pragma unroll
            for (int u = 0; u < 4; ++u) {
                const int bi = tid + 256 * (half * 4 + u);
                const int r2 = bi >> 7, blk2 = bi & 127;
                *(f16x8*)&Hs[((r2 << 7) + (blk2 ^ (r2 & 7))) * 8] =
                    cvt8(q[2 * u], q[2 * u + 1]);
            }
        }
        __syncthreads();
    }
}

extern "C" void kernel_launch(void* const* d_in, const int* in_sizes, int n_in,
                              void* d_out, int out_size, void* d_ws, size_t ws_size,
                              hipStream_t stream) {
    const float* x    = (const float*)d_in[0];   // [T][B][D]
    const float* h0   = (const float*)d_in[1];   // [B][D]
    const float* Wx   = (const float*)d_in[2];   // [D][D]
    const float* Wh   = (const float*)d_in[3];   // [D][D]
    const float* bias = (const float*)d_in[4];   // [D]

    float* hs    = (float*)d_out;
    float* h_all = hs + (size_t)T_STEPS * BATCH * DIM;

    int*       flags = (int*)d_ws;                        // 2 KB (padded flags)
    _Float16*  P     = (_Float16*)((char*)d_ws + 4096);   // 2 MB packed W_h

    flag_init<<<1, NWG * 16, 0, stream>>>(flags);
    conv_pack<<<(DIM * DIM) / 256, 256, 0, stream>>>(Wh, P);

    dim3 g((T_STEPS * BATCH) / BM, DIM / BN);
    gemm_xw<<<g, 256, 0, stream>>>(x, Wx, bias, h_all + (size_t)BATCH * DIM);

    elman_rec<<<NWG, 256, 0, stream>>>(h0, P, hs, h_all, flags);
}

// Round 6
// 7594.938 us; speedup vs baseline: 8.7074x; 1.3419x over previous
//
#include <hip/hip_runtime.h>
#include <hip/hip_fp16.h>

#define T_STEPS 2048
#define BATCH   32
#define DIM     1024
#define NWG     32      // rec workgroups; wg owns 32 output cols
#define WCOLS   32

typedef _Float16 half2_t __attribute__((ext_vector_type(2)));
typedef _Float16 f16x8 __attribute__((ext_vector_type(8)));
typedef float    f32x4 __attribute__((ext_vector_type(4)));

__device__ __forceinline__ f16x8 cvt8(f32x4 a, f32x4 b) {
    f16x8 r;
    r[0]=(_Float16)a[0]; r[1]=(_Float16)a[1]; r[2]=(_Float16)a[2]; r[3]=(_Float16)a[3];
    r[4]=(_Float16)b[0]; r[5]=(_Float16)b[1]; r[6]=(_Float16)b[2]; r[7]=(_Float16)b[3];
    return r;
}

// ---------------------------------------------------------------------------
// flags zeroed every launch (graph replays don't re-poison d_ws)
// ---------------------------------------------------------------------------
__global__ void flag_init(int* __restrict__ flags) { flags[threadIdx.x] = 0; }

// ---------------------------------------------------------------------------
// repack W_h (fp32 [k][n]) -> f16, B-fragment-swizzled blocks:
// P[n][pos][e] where blk=k>>3, e=k&7, pos = blk ^ (n&7)
// ---------------------------------------------------------------------------
__global__ void conv_pack(const float* __restrict__ Wh, _Float16* __restrict__ P) {
    const int idx = blockIdx.x * blockDim.x + threadIdx.x;  // DIM*DIM
    const int k = idx >> 10, n = idx & (DIM - 1);
    const int pos = (k >> 3) ^ (n & 7);
    P[(size_t)n * 1024 + pos * 8 + (k & 7)] = (_Float16)Wh[idx];
}

// ---------------------------------------------------------------------------
// xW = x @ W_x + b  (validated rounds 1-5, unchanged) -> h_all[1:]
// ---------------------------------------------------------------------------
#define BM 128
#define BN 128
#define BK 32
#define LDT 40

__global__ __launch_bounds__(256) void gemm_xw(
    const float* __restrict__ X, const float* __restrict__ Wx,
    const float* __restrict__ bias, float* __restrict__ out)
{
    __shared__ _Float16 As[BM][LDT];
    __shared__ _Float16 Bs[BN][LDT];

    const int tid = threadIdx.x;
    const int m0 = blockIdx.x * BM, n0 = blockIdx.y * BN;
    const int lane = tid & 63, wid = tid >> 6;
    const int wm = (wid >> 1) * 64, wn = (wid & 1) * 64;
    const int lr = lane & 15, lk = (lane >> 4) * 8;
    const int ar = tid >> 1, ac = (tid & 1) * 16;
    const int bk = tid >> 3, bn = (tid & 7) * 16;

    f32x4 acc[4][4] = {};

    for (int k0 = 0; k0 < DIM; k0 += BK) {
        __syncthreads();
        {
            const float* src = X + (size_t)(m0 + ar) * DIM + k0 + ac;
            float4 q0 = *(const float4*)(src + 0);
            float4 q1 = *(const float4*)(src + 4);
            float4 q2 = *(const float4*)(src + 8);
            float4 q3 = *(const float4*)(src + 12);
            f16x8 p0, p1;
            p0[0]=(_Float16)q0.x; p0[1]=(_Float16)q0.y; p0[2]=(_Float16)q0.z; p0[3]=(_Float16)q0.w;
            p0[4]=(_Float16)q1.x; p0[5]=(_Float16)q1.y; p0[6]=(_Float16)q1.z; p0[7]=(_Float16)q1.w;
            p1[0]=(_Float16)q2.x; p1[1]=(_Float16)q2.y; p1[2]=(_Float16)q2.z; p1[3]=(_Float16)q2.w;
            p1[4]=(_Float16)q3.x; p1[5]=(_Float16)q3.y; p1[6]=(_Float16)q3.z; p1[7]=(_Float16)q3.w;
            *(f16x8*)&As[ar][ac] = p0;
            *(f16x8*)&As[ar][ac + 8] = p1;
        }
        {
            const float* src = Wx + (size_t)(k0 + bk) * DIM + n0 + bn;
            float4 q0 = *(const float4*)(src + 0);
            float4 q1 = *(const float4*)(src + 4);
            float4 q2 = *(const float4*)(src + 8);
            float4 q3 = *(const float4*)(src + 12);
            float vv[16];
            *(float4*)&vv[0] = q0; *(float4*)&vv[4] = q1;
            *(float4*)&vv[8] = q2; *(float4*)&vv[12] = q3;
            #pragma unroll
            for (int i = 0; i < 16; ++i) Bs[bn + i][bk] = (_Float16)vv[i];
        }
        __syncthreads();
        f16x8 a[4], bb[4];
        #pragma unroll
        for (int f = 0; f < 4; ++f) a[f]  = *(const f16x8*)&As[wm + f * 16 + lr][lk];
        #pragma unroll
        for (int f = 0; f < 4; ++f) bb[f] = *(const f16x8*)&Bs[wn + f * 16 + lr][lk];
        #pragma unroll
        for (int i = 0; i < 4; ++i)
            #pragma unroll
            for (int j = 0; j < 4; ++j)
                acc[i][j] = __builtin_amdgcn_mfma_f32_16x16x32_f16(a[i], bb[j], acc[i][j], 0, 0, 0);
    }

    #pragma unroll
    for (int i = 0; i < 4; ++i)
        #pragma unroll
        for (int j = 0; j < 4; ++j) {
            const int col = n0 + wn + j * 16 + lr;
            const float bv = bias[col];
            #pragma unroll
            for (int r = 0; r < 4; ++r) {
                const int row = m0 + wm + i * 16 + (lane >> 4) * 4 + r;
                __builtin_nontemporal_store(acc[i][j][r] + bv, out + (size_t)row * DIM + col);
            }
        }
}

// ---------------------------------------------------------------------------
// recurrence: 32 wgs x 256 thr. Per step: MFMA (K-split over 4 waves) ->
// emit tanh -> outputs (plain) + f16 publish to double-buffered d_ws ring
// (sc0sc1) -> flag -> PER-WAVE poll of the 8 producers of its own k-slice ->
// per-wave single-RTT reload (16 in-flight 16B loads) -> LDS. 2 barriers/step.
// Ring depth 2 is safe: flag f  =>  that wg finished reading h_{f-1} (its
// reload of h_{f-1} precedes publishing flag f), and a producer enters step t
// only after all flags >= t.
// ---------------------------------------------------------------------------
__global__ __launch_bounds__(256, 1) void elman_rec(
    const float* __restrict__ h0, const _Float16* __restrict__ P,
    float* __restrict__ hs, float* __restrict__ h_all,
    int* __restrict__ flags, _Float16* __restrict__ xchg)
{
    __shared__ _Float16 Hs[32 * 128 * 8];   // [row][pos][8]  64 KB
    __shared__ _Float16 Ws[32 * 128 * 8];   // [colL][pos][8] 64 KB
    __shared__ float    Ht2[4][32][36];     // K-split partials, 18 KB

    const int wg  = blockIdx.x;
    const int tid = threadIdx.x;
    const int w = tid >> 6, lane = tid & 63, lr = lane & 15, kg = lane >> 4;
    const int wcol0 = wg * WCOLS;

    // ---- stage W slice (swizzle pre-baked by conv_pack)
    {
        const uint4* src = (const uint4*)(P + (size_t)wcol0 * 1024);
        uint4* dst = (uint4*)Ws;
        #pragma unroll
        for (int j = 0; j < 16; ++j) dst[tid + 256 * j] = src[tid + 256 * j];
    }
    // ---- stage h0 -> Hs; wg0 writes h_all[0] = h0
    #pragma unroll
    for (int j = 0; j < 16; ++j) {
        const int bi = tid + 256 * j;
        const int r = bi >> 7, blk = bi & 127;
        f32x4 q0 = *(const f32x4*)(h0 + (size_t)r * DIM + blk * 8);
        f32x4 q1 = *(const f32x4*)(h0 + (size_t)r * DIM + blk * 8 + 4);
        *(f16x8*)&Hs[((r << 7) + (blk ^ (r & 7))) * 8] = cvt8(q0, q1);
        if (wg == 0) {
            *(f32x4*)(h_all + (size_t)r * DIM + blk * 8)     = q0;
            *(f32x4*)(h_all + (size_t)r * DIM + blk * 8 + 4) = q1;
        }
    }
    __syncthreads();

    const int er = tid >> 3, ec4 = (tid & 7) * 4;   // emit coords
    const int rl_rh  = lane >> 5;                   // reload: row half (0/1)
    const int rl_blk = 32 * w + (lane & 31);        // reload: 8-f16 block index

    for (int t = 0; t < T_STEPS; ++t) {
        float* slot = h_all + (size_t)(t + 1) * (BATCH * DIM);

        // xW for emit (plain load; hidden under MFMA)
        f32x4 xw = *(const f32x4*)(slot + (size_t)er * DIM + wcol0 + ec4);

        // ---- MFMA, K-split: wave w covers k-blocks [32w, 32w+32)
        f32x4 a00 = {0,0,0,0}, a01 = {0,0,0,0}, a10 = {0,0,0,0}, a11 = {0,0,0,0};
        #pragma unroll
        for (int q = 0; q < 8; ++q) {
            const int blk = (w * 8 + q) * 4 + kg;
            const int pa = blk ^ (lr & 7);
            f16x8 A0 = *(const f16x8*)&Hs[((lr << 7)        + pa) * 8];
            f16x8 A1 = *(const f16x8*)&Hs[(((16 + lr) << 7) + pa) * 8];
            f16x8 B0 = *(const f16x8*)&Ws[((lr << 7)        + pa) * 8];
            f16x8 B1 = *(const f16x8*)&Ws[(((16 + lr) << 7) + pa) * 8];
            a00 = __builtin_amdgcn_mfma_f32_16x16x32_f16(A0, B0, a00, 0, 0, 0);
            a01 = __builtin_amdgcn_mfma_f32_16x16x32_f16(A0, B1, a01, 0, 0, 0);
            a10 = __builtin_amdgcn_mfma_f32_16x16x32_f16(A1, B0, a10, 0, 0, 0);
            a11 = __builtin_amdgcn_mfma_f32_16x16x32_f16(A1, B1, a11, 0, 0, 0);
        }
        #pragma unroll
        for (int r = 0; r < 4; ++r) {
            Ht2[w][kg * 4 + r]      [lr]      = a00[r];
            Ht2[w][kg * 4 + r]      [16 + lr] = a01[r];
            Ht2[w][16 + kg * 4 + r] [lr]      = a10[r];
            Ht2[w][16 + kg * 4 + r] [16 + lr] = a11[r];
        }
        __syncthreads();

        // ---- emit: reduce partials, +xW, tanh
        f32x4 z = xw;
        #pragma unroll
        for (int ww = 0; ww < 4; ++ww) z += *(const f32x4*)&Ht2[ww][er][ec4];
        f32x4 h;
        #pragma unroll
        for (int i = 0; i < 4; ++i) {
            const float e = __expf(2.0f * z[i]);
            h[i] = 1.0f - 2.0f / (e + 1.0f);
        }
        // outputs: plain/nontemporal (own wg is the only reader of its cols)
        __builtin_nontemporal_store(h, (f32x4*)(hs + (size_t)t * (BATCH * DIM)
                                                + (size_t)er * DIM + wcol0 + ec4));
        *(f32x4*)(slot + (size_t)er * DIM + wcol0 + ec4) = h;
        // publish f16 to the exchange ring (8B/thread, coherent)
        {
            half2_t lo, hi;
            lo[0] = (_Float16)h[0]; lo[1] = (_Float16)h[1];
            hi[0] = (_Float16)h[2]; hi[1] = (_Float16)h[3];
            uint2 pk;
            pk.x = __builtin_bit_cast(unsigned, lo);
            pk.y = __builtin_bit_cast(unsigned, hi);
            _Float16* xp = xchg + (size_t)((t + 1) & 1) * (BATCH * DIM)
                         + (size_t)er * DIM + wcol0 + ec4;
            asm volatile("global_store_dwordx2 %0, %1, off sc0 sc1"
                         :: "v"(xp), "v"(pk) : "memory");
        }

        if (t == T_STEPS - 1) break;

        asm volatile("s_waitcnt vmcnt(0)" ::: "memory");   // publish retired
        __syncthreads();
        if (tid == 0)
            __hip_atomic_store(flags + wg * 16, t + 1, __ATOMIC_RELAXED,
                               __HIP_MEMORY_SCOPE_AGENT);

        // ---- per-wave: poll only the 8 producers of this wave's k-slice
        if (lane < 8) {
            const int* fp = flags + (w * 8 + lane) * 16;
            int g = 0;
            while (__hip_atomic_load(fp, __ATOMIC_RELAXED,
                                     __HIP_MEMORY_SCOPE_AGENT) < t + 1) {
                if (++g > (1 << 20)) break;   // fail loud, not hung
            }
        }

        // ---- per-wave reload of own k-slice: 16 in-flight loads, one RTT
        const _Float16* xb = xchg + (size_t)((t + 1) & 1) * (BATCH * DIM);
        uint4 q[16];
        #pragma unroll
        for (int i = 0; i < 16; ++i) {
            const int row = 2 * i + rl_rh;
            const _Float16* ap = xb + (size_t)row * DIM + rl_blk * 8;
            asm volatile("global_load_dwordx4 %0, %1, off sc0 sc1"
                         : "=v"(q[i]) : "v"(ap) : "memory");
        }
        asm volatile("s_waitcnt vmcnt(0)" ::: "memory");
        __builtin_amdgcn_sched_barrier(0);
        #pragma unroll
        for (int i = 0; i < 16; ++i) {
            const int row = 2 * i + rl_rh;
            *(uint4*)&Hs[((row << 7) + (rl_blk ^ (row & 7))) * 8] = q[i];
        }
        // no barrier: next MFMA reads only this wave's own k-blocks
    }
}

extern "C" void kernel_launch(void* const* d_in, const int* in_sizes, int n_in,
                              void* d_out, int out_size, void* d_ws, size_t ws_size,
                              hipStream_t stream) {
    const float* x    = (const float*)d_in[0];   // [T][B][D]
    const float* h0   = (const float*)d_in[1];   // [B][D]
    const float* Wx   = (const float*)d_in[2];   // [D][D]
    const float* Wh   = (const float*)d_in[3];   // [D][D]
    const float* bias = (const float*)d_in[4];   // [D]

    float* hs    = (float*)d_out;
    float* h_all = hs + (size_t)T_STEPS * BATCH * DIM;

    int*       flags = (int*)d_ws;                              // 2 KB
    _Float16*  xchg  = (_Float16*)((char*)d_ws + 4096);         // 128 KB ring
    _Float16*  P     = (_Float16*)((char*)d_ws + 4096 + 131072);// 2 MB packed W_h

    flag_init<<<1, NWG * 16, 0, stream>>>(flags);
    conv_pack<<<(DIM * DIM) / 256, 256, 0, stream>>>(Wh, P);

    dim3 g((T_STEPS * BATCH) / BM, DIM / BN);
    gemm_xw<<<g, 256, 0, stream>>>(x, Wx, bias, h_all + (size_t)BATCH * DIM);

    elman_rec<<<NWG, 256, 0, stream>>>(h0, P, hs, h_all, flags, xchg);
}

// Round 8
// 7424.117 us; speedup vs baseline: 8.9077x; 1.0230x over previous
//
#include <hip/hip_runtime.h>
#include <hip/hip_fp16.h>

#define T_STEPS 2048
#define BATCH   32
#define DIM     1024
#define NWG     32      // rec workgroups; wg owns 32 output cols
#define WCOLS   32

typedef _Float16 half2_t __attribute__((ext_vector_type(2)));
typedef _Float16 f16x8 __attribute__((ext_vector_type(8)));
typedef float    f32x4 __attribute__((ext_vector_type(4)));

__device__ __forceinline__ f16x8 cvt8(f32x4 a, f32x4 b) {
    f16x8 r;
    r[0]=(_Float16)a[0]; r[1]=(_Float16)a[1]; r[2]=(_Float16)a[2]; r[3]=(_Float16)a[3];
    r[4]=(_Float16)b[0]; r[5]=(_Float16)b[1]; r[6]=(_Float16)b[2]; r[7]=(_Float16)b[3];
    return r;
}

// ---------------------------------------------------------------------------
// flags zeroed every launch (graph replays don't re-poison d_ws)
// ---------------------------------------------------------------------------
__global__ void flag_init(int* __restrict__ flags) { flags[threadIdx.x] = 0; }

// ---------------------------------------------------------------------------
// repack W_h (fp32 [k][n]) -> f16, B-fragment-swizzled blocks:
// P[n][pos][e] where blk=k>>3, e=k&7, pos = blk ^ (n&7)
// ---------------------------------------------------------------------------
__global__ void conv_pack(const float* __restrict__ Wh, _Float16* __restrict__ P) {
    const int idx = blockIdx.x * blockDim.x + threadIdx.x;  // DIM*DIM
    const int k = idx >> 10, n = idx & (DIM - 1);
    const int pos = (k >> 3) ^ (n & 7);
    P[(size_t)n * 1024 + pos * 8 + (k & 7)] = (_Float16)Wh[idx];
}

// ---------------------------------------------------------------------------
// xW = x @ W_x + b  (validated rounds 1-7, unchanged) -> h_all[1:]
// ---------------------------------------------------------------------------
#define BM 128
#define BN 128
#define BK 32
#define LDT 40

__global__ __launch_bounds__(256) void gemm_xw(
    const float* __restrict__ X, const float* __restrict__ Wx,
    const float* __restrict__ bias, float* __restrict__ out)
{
    __shared__ _Float16 As[BM][LDT];
    __shared__ _Float16 Bs[BN][LDT];

    const int tid = threadIdx.x;
    const int m0 = blockIdx.x * BM, n0 = blockIdx.y * BN;
    const int lane = tid & 63, wid = tid >> 6;
    const int wm = (wid >> 1) * 64, wn = (wid & 1) * 64;
    const int lr = lane & 15, lk = (lane >> 4) * 8;
    const int ar = tid >> 1, ac = (tid & 1) * 16;
    const int bk = tid >> 3, bn = (tid & 7) * 16;

    f32x4 acc[4][4] = {};

    for (int k0 = 0; k0 < DIM; k0 += BK) {
        __syncthreads();
        {
            const float* src = X + (size_t)(m0 + ar) * DIM + k0 + ac;
            float4 q0 = *(const float4*)(src + 0);
            float4 q1 = *(const float4*)(src + 4);
            float4 q2 = *(const float4*)(src + 8);
            float4 q3 = *(const float4*)(src + 12);
            f16x8 p0, p1;
            p0[0]=(_Float16)q0.x; p0[1]=(_Float16)q0.y; p0[2]=(_Float16)q0.z; p0[3]=(_Float16)q0.w;
            p0[4]=(_Float16)q1.x; p0[5]=(_Float16)q1.y; p0[6]=(_Float16)q1.z; p0[7]=(_Float16)q1.w;
            p1[0]=(_Float16)q2.x; p1[1]=(_Float16)q2.y; p1[2]=(_Float16)q2.z; p1[3]=(_Float16)q2.w;
            p1[4]=(_Float16)q3.x; p1[5]=(_Float16)q3.y; p1[6]=(_Float16)q3.z; p1[7]=(_Float16)q3.w;
            *(f16x8*)&As[ar][ac] = p0;
            *(f16x8*)&As[ar][ac + 8] = p1;
        }
        {
            const float* src = Wx + (size_t)(k0 + bk) * DIM + n0 + bn;
            float4 q0 = *(const float4*)(src + 0);
            float4 q1 = *(const float4*)(src + 4);
            float4 q2 = *(const float4*)(src + 8);
            float4 q3 = *(const float4*)(src + 12);
            float vv[16];
            *(float4*)&vv[0] = q0; *(float4*)&vv[4] = q1;
            *(float4*)&vv[8] = q2; *(float4*)&vv[12] = q3;
            #pragma unroll
            for (int i = 0; i < 16; ++i) Bs[bn + i][bk] = (_Float16)vv[i];
        }
        __syncthreads();
        f16x8 a[4], bb[4];
        #pragma unroll
        for (int f = 0; f < 4; ++f) a[f]  = *(const f16x8*)&As[wm + f * 16 + lr][lk];
        #pragma unroll
        for (int f = 0; f < 4; ++f) bb[f] = *(const f16x8*)&Bs[wn + f * 16 + lr][lk];
        #pragma unroll
        for (int i = 0; i < 4; ++i)
            #pragma unroll
            for (int j = 0; j < 4; ++j)
                acc[i][j] = __builtin_amdgcn_mfma_f32_16x16x32_f16(a[i], bb[j], acc[i][j], 0, 0, 0);
    }

    #pragma unroll
    for (int i = 0; i < 4; ++i)
        #pragma unroll
        for (int j = 0; j < 4; ++j) {
            const int col = n0 + wn + j * 16 + lr;
            const float bv = bias[col];
            #pragma unroll
            for (int r = 0; r < 4; ++r) {
                const int row = m0 + wm + i * 16 + (lane >> 4) * 4 + r;
                __builtin_nontemporal_store(acc[i][j][r] + bv, out + (size_t)row * DIM + col);
            }
        }
}

// ---------------------------------------------------------------------------
// recurrence: 32 wgs x 256 thr. Per step: MFMA (K-split over 4 waves) ->
// emit tanh -> f16 publish to double-buffered d_ws ring (sc1 = device scope,
// L3 coherence point) -> EXPLICIT vmcnt(0) drain (inline-asm stores are
// invisible to the compiler's barrier waitcnt pass — round 7 raced without
// this) -> barrier -> flag -> per-wave poll of the 8 producers of its own
// k-slice -> per-wave single-RTT sc1 reload -> LDS. Ring depth 2 safe:
// flag f => wg finished reading h_{f-1}; producers enter step t only after
// all flags >= t.
// ---------------------------------------------------------------------------
__global__ __launch_bounds__(256, 1) void elman_rec(
    const float* __restrict__ h0, const _Float16* __restrict__ P,
    float* __restrict__ hs, float* __restrict__ h_all,
    int* __restrict__ flags, _Float16* __restrict__ xchg)
{
    __shared__ _Float16 Hs[32 * 128 * 8];   // [row][pos][8]  64 KB
    __shared__ _Float16 Ws[32 * 128 * 8];   // [colL][pos][8] 64 KB
    __shared__ float    Ht2[4][32][36];     // K-split partials, 18 KB

    const int wg  = blockIdx.x;
    const int tid = threadIdx.x;
    const int w = tid >> 6, lane = tid & 63, lr = lane & 15, kg = lane >> 4;
    const int wcol0 = wg * WCOLS;

    // ---- stage W slice (swizzle pre-baked by conv_pack)
    {
        const uint4* src = (const uint4*)(P + (size_t)wcol0 * 1024);
        uint4* dst = (uint4*)Ws;
        #pragma unroll
        for (int j = 0; j < 16; ++j) dst[tid + 256 * j] = src[tid + 256 * j];
    }
    // ---- stage h0 -> Hs; wg0 writes h_all[0] = h0
    #pragma unroll
    for (int j = 0; j < 16; ++j) {
        const int bi = tid + 256 * j;
        const int r = bi >> 7, blk = bi & 127;
        f32x4 q0 = *(const f32x4*)(h0 + (size_t)r * DIM + blk * 8);
        f32x4 q1 = *(const f32x4*)(h0 + (size_t)r * DIM + blk * 8 + 4);
        *(f16x8*)&Hs[((r << 7) + (blk ^ (r & 7))) * 8] = cvt8(q0, q1);
        if (wg == 0) {
            *(f32x4*)(h_all + (size_t)r * DIM + blk * 8)     = q0;
            *(f32x4*)(h_all + (size_t)r * DIM + blk * 8 + 4) = q1;
        }
    }
    __syncthreads();

    const int er = tid >> 3, ec4 = (tid & 7) * 4;   // emit coords
    const int rl_rh  = lane >> 5;                   // reload: row half (0/1)
    const int rl_blk = 32 * w + (lane & 31);        // reload: 8-f16 block index

    for (int t = 0; t < T_STEPS; ++t) {
        float* slot = h_all + (size_t)(t + 1) * (BATCH * DIM);

        // xW for emit (plain load; hidden under MFMA)
        f32x4 xw = *(const f32x4*)(slot + (size_t)er * DIM + wcol0 + ec4);

        // ---- MFMA, K-split: wave w covers k-blocks [32w, 32w+32)
        f32x4 a00 = {0,0,0,0}, a01 = {0,0,0,0}, a10 = {0,0,0,0}, a11 = {0,0,0,0};
        #pragma unroll
        for (int q = 0; q < 8; ++q) {
            const int blk = (w * 8 + q) * 4 + kg;
            const int pa = blk ^ (lr & 7);
            f16x8 A0 = *(const f16x8*)&Hs[((lr << 7)        + pa) * 8];
            f16x8 A1 = *(const f16x8*)&Hs[(((16 + lr) << 7) + pa) * 8];
            f16x8 B0 = *(const f16x8*)&Ws[((lr << 7)        + pa) * 8];
            f16x8 B1 = *(const f16x8*)&Ws[(((16 + lr) << 7) + pa) * 8];
            a00 = __builtin_amdgcn_mfma_f32_16x16x32_f16(A0, B0, a00, 0, 0, 0);
            a01 = __builtin_amdgcn_mfma_f32_16x16x32_f16(A0, B1, a01, 0, 0, 0);
            a10 = __builtin_amdgcn_mfma_f32_16x16x32_f16(A1, B0, a10, 0, 0, 0);
            a11 = __builtin_amdgcn_mfma_f32_16x16x32_f16(A1, B1, a11, 0, 0, 0);
        }
        #pragma unroll
        for (int r = 0; r < 4; ++r) {
            Ht2[w][kg * 4 + r]      [lr]      = a00[r];
            Ht2[w][kg * 4 + r]      [16 + lr] = a01[r];
            Ht2[w][16 + kg * 4 + r] [lr]      = a10[r];
            Ht2[w][16 + kg * 4 + r] [16 + lr] = a11[r];
        }
        __syncthreads();

        // ---- emit: reduce partials, +xW, tanh
        f32x4 z = xw;
        #pragma unroll
        for (int ww = 0; ww < 4; ++ww) z += *(const f32x4*)&Ht2[ww][er][ec4];
        f32x4 h;
        #pragma unroll
        for (int i = 0; i < 4; ++i) {
            const float e = __expf(2.0f * z[i]);
            h[i] = 1.0f - 2.0f / (e + 1.0f);
        }
        // publish FIRST (device-scope sc1 -> L3; its ack is the critical drain)
        {
            half2_t lo, hi;
            lo[0] = (_Float16)h[0]; lo[1] = (_Float16)h[1];
            hi[0] = (_Float16)h[2]; hi[1] = (_Float16)h[3];
            uint2 pk;
            pk.x = __builtin_bit_cast(unsigned, lo);
            pk.y = __builtin_bit_cast(unsigned, hi);
            _Float16* xp = xchg + (size_t)((t + 1) & 1) * (BATCH * DIM)
                         + (size_t)er * DIM + wcol0 + ec4;
            asm volatile("global_store_dwordx2 %0, %1, off sc1"
                         :: "v"(xp), "v"(pk) : "memory");
        }
        // outputs: plain/nontemporal (ack at L2, cheap; own wg only reader)
        __builtin_nontemporal_store(h, (f32x4*)(hs + (size_t)t * (BATCH * DIM)
                                                + (size_t)er * DIM + wcol0 + ec4));
        *(f32x4*)(slot + (size_t)er * DIM + wcol0 + ec4) = h;

        if (t == T_STEPS - 1) break;

        // explicit drain: inline-asm stores are NOT covered by the barrier's
        // compiler-inserted waitcnt (round-7 race). Must retire before flag.
        asm volatile("s_waitcnt vmcnt(0)" ::: "memory");
        __syncthreads();
        if (tid == 0)
            __hip_atomic_store(flags + wg * 16, t + 1, __ATOMIC_RELAXED,
                               __HIP_MEMORY_SCOPE_AGENT);

        // ---- per-wave: poll only the 8 producers of this wave's k-slice
        if (lane < 8) {
            const int* fp = flags + (w * 8 + lane) * 16;
            int g = 0;
            while (__hip_atomic_load(fp, __ATOMIC_RELAXED,
                                     __HIP_MEMORY_SCOPE_AGENT) < t + 1) {
                if (++g > (1 << 20)) break;   // fail loud, not hung
            }
        }

        // ---- per-wave reload of own k-slice: 16 in-flight sc1 loads, one RTT
        const _Float16* xb = xchg + (size_t)((t + 1) & 1) * (BATCH * DIM);
        uint4 q[16];
        #pragma unroll
        for (int i = 0; i < 16; ++i) {
            const int row = 2 * i + rl_rh;
            const _Float16* ap = xb + (size_t)row * DIM + rl_blk * 8;
            asm volatile("global_load_dwordx4 %0, %1, off sc1"
                         : "=v"(q[i]) : "v"(ap) : "memory");
        }
        asm volatile("s_waitcnt vmcnt(0)" ::: "memory");
        __builtin_amdgcn_sched_barrier(0);
        #pragma unroll
        for (int i = 0; i < 16; ++i) {
            const int row = 2 * i + rl_rh;
            *(uint4*)&Hs[((row << 7) + (rl_blk ^ (row & 7))) * 8] = q[i];
        }
        // no barrier: next MFMA reads only this wave's own k-blocks
    }
}

extern "C" void kernel_launch(void* const* d_in, const int* in_sizes, int n_in,
                              void* d_out, int out_size, void* d_ws, size_t ws_size,
                              hipStream_t stream) {
    const float* x    = (const float*)d_in[0];   // [T][B][D]
    const float* h0   = (const float*)d_in[1];   // [B][D]
    const float* Wx   = (const float*)d_in[2];   // [D][D]
    const float* Wh   = (const float*)d_in[3];   // [D][D]
    const float* bias = (const float*)d_in[4];   // [D]

    float* hs    = (float*)d_out;
    float* h_all = hs + (size_t)T_STEPS * BATCH * DIM;

    int*       flags = (int*)d_ws;                              // 2 KB
    _Float16*  xchg  = (_Float16*)((char*)d_ws + 4096);         // 128 KB ring
    _Float16*  P     = (_Float16*)((char*)d_ws + 4096 + 131072);// 2 MB packed W_h

    flag_init<<<1, NWG * 16, 0, stream>>>(flags);
    conv_pack<<<(DIM * DIM) / 256, 256, 0, stream>>>(Wh, P);

    dim3 g((T_STEPS * BATCH) / BM, DIM / BN);
    gemm_xw<<<g, 256, 0, stream>>>(x, Wx, bias, h_all + (size_t)BATCH * DIM);

    elman_rec<<<NWG, 256, 0, stream>>>(h0, P, hs, h_all, flags, xchg);
}